// Round 13
// baseline (161.527 us; speedup 1.0000x reference)
//
#include <hip/hip_runtime.h>

#define N_NODES 40000
#define N_EDGES 640000
#define D 128
#define CAP 64            // bucket slots/node; in-deg ~ Poisson(16), P(>64) ~ 1e-13
#define PREP_GRID 1280    // 2 independent edge chains per thread
#define XPITCH 136        // xs row pitch (floats); 544 B rows, 32B-aligned

typedef __attribute__((ext_vector_type(8))) short short8;
typedef __attribute__((ext_vector_type(4))) float float4v;

// round-to-nearest-even fp32 -> bf16 bits
static __device__ __forceinline__ unsigned bf16_rne(float f) {
    unsigned u = __float_as_uint(f);
    return (u + 0x7FFFu + ((u >> 16) & 1u)) >> 16;
}
static __device__ __forceinline__ unsigned pack2(float a, float b) {
    return bf16_rne(a) | (bf16_rne(b) << 16);
}

// ---------------------------------------------------------------------------
// K1: (a) edge hist + bucket scatter where the scatter is a native 4B
//     atomicOr (slot parity from rank) instead of a u16 plain store -> no
//     partial-line ECC-RMW flush path (the R7-measured 48.5MB WRITE
//     amplification). Word layout matches agg's u32 row reads exactly:
//     word w = rank 2w (low 16) | rank 2w+1 (high 16). Bucket is memset-0.
//     (b) fp32->bf16 feature pack; (c) W -> bf16 B-fragment order.
// ---------------------------------------------------------------------------
__global__ __launch_bounds__(256) void prep_kernel(
    const float* __restrict__ feat,
    const int*   __restrict__ src,
    const int*   __restrict__ dst,
    const float* __restrict__ W,
    unsigned*    __restrict__ featb,    // [N*D/2] packed 2xbf16
    unsigned*    __restrict__ wfrag,    // [8192] packed 2xbf16, frag order
    int*         __restrict__ deg,      // [N] zeroed by memset
    unsigned*    __restrict__ bucket)   // [N*CAP/2] u32 words, zeroed by memset
{
    const int g  = blockIdx.x * 256 + threadIdx.x;
    const int GT = PREP_GRID * 256;       // 327680

    // ---- edge phase: two independent chains per thread ----
    {
        const int e0 = g;                 // < 327680 < N_EDGES always
        const int e1 = g + GT;
        const bool h1 = e1 < N_EDGES;
        int d0 = dst[e0];
        int s0 = src[e0];
        int d1 = h1 ? dst[e1] : 0;
        int s1 = h1 ? src[e1] : 0;
        int r0 = atomicAdd(&deg[d0], 1);              // both atomics in flight
        int r1 = h1 ? atomicAdd(&deg[d1], 1) : CAP;
        if (r0 < CAP)
            atomicOr(&bucket[d0 * (CAP / 2) + (r0 >> 1)],
                     (unsigned)s0 << ((r0 & 1) * 16));
        if (r1 < CAP)
            atomicOr(&bucket[d1 * (CAP / 2) + (r1 >> 1)],
                     (unsigned)s1 << ((r1 & 1) * 16));
    }

    // ---- bf16 feature pack (streams under other waves' atomic stalls) ----
    for (int i = g; i < N_NODES * D / 4; i += GT) {
        float4 f = reinterpret_cast<const float4*>(feat)[i];
        uint2 p;
        p.x = pack2(f.x, f.y);
        p.y = pack2(f.z, f.w);
        reinterpret_cast<uint2*>(featb)[i] = p;
    }

    // ---- W -> B-fragment order (8 ntiles x 4 ktiles x 64 lanes) ----
    if (g < 32 * 64) {
        const int tile = g >> 6, lane = g & 63;
        const int nt = tile >> 2, kt = tile & 3;
        const int n = nt * 16 + (lane & 15);
        const int k = kt * 32 + (lane >> 4) * 8;
        const float* wp = W + (size_t)n * D + k;
        uint4 p;
        p.x = pack2(wp[0], wp[1]);
        p.y = pack2(wp[2], wp[3]);
        p.z = pack2(wp[4], wp[5]);
        p.w = pack2(wp[6], wp[7]);
        reinterpret_cast<uint4*>(wfrag)[g] = p;
    }
}

// ---------------------------------------------------------------------------
// K2 (= R11/R9 proven best): fused aggregate + MFMA linear. Block = 512 thr
//     = 8 waves = 16 nodes. Wave owns nodes {2w, 2w+1}; bucket rows
//     preloaded as u32 words (one coalesced read each), indices via __shfl;
//     the two nodes' gather loops INTERLEAVED (16 gathers in flight).
//     sum featb[src] * feat[n]/deg (factorized u_mul_v) -> LDS xs.
//     GEMM: wave w computes ntile w via 4x mfma_f32_16x16x32_bf16.
// ---------------------------------------------------------------------------
__global__ __launch_bounds__(512) void agg_gemm(
    const float*    __restrict__ feat,
    const unsigned* __restrict__ featb,
    const unsigned* __restrict__ wfrag,
    const int*      __restrict__ deg,
    const unsigned* __restrict__ bucket,
    const float*    __restrict__ bias,
    float*          __restrict__ out)
{
    __shared__ float xs[16 * XPITCH];   // 8704 B
    const int t     = threadIdx.x;
    const int wave  = t >> 6;           // 0..7
    const int lane  = t & 63;
    const int node0 = blockIdx.x * 16;

    const int n0  = node0 + wave * 2;
    const int dg0 = min(deg[n0],     CAP);
    const int dg1 = min(deg[n0 + 1], CAP);
    const unsigned iw0 = bucket[(size_t)n0 * (CAP / 2) + (lane & 31)];
    const unsigned iw1 = bucket[(size_t)(n0 + 1) * (CAP / 2) + (lane & 31)];

    float2 acc0 = make_float2(0.f, 0.f);
    float2 acc1 = make_float2(0.f, 0.f);

    #define IDX0(i) ({ int w_ = __shfl((int)iw0, (i) >> 1, 64); ((i) & 1) ? ((w_ >> 16) & 0xFFFF) : (w_ & 0xFFFF); })
    #define IDX1(i) ({ int w_ = __shfl((int)iw1, (i) >> 1, 64); ((i) & 1) ? ((w_ >> 16) & 0xFFFF) : (w_ & 0xFFFF); })

    int i0 = 0, i1 = 0;
    while (i0 + 8 <= dg0 && i1 + 8 <= dg1) {   // 16 gathers in flight
        unsigned va[8], vb[8];
        #pragma unroll
        for (int j = 0; j < 8; ++j) va[j] = featb[((size_t)IDX0(i0 + j) << 6) + lane];
        #pragma unroll
        for (int j = 0; j < 8; ++j) vb[j] = featb[((size_t)IDX1(i1 + j) << 6) + lane];
        #pragma unroll
        for (int j = 0; j < 8; ++j) {
            acc0.x += __uint_as_float(va[j] << 16);
            acc0.y += __uint_as_float(va[j] & 0xFFFF0000u);
            acc1.x += __uint_as_float(vb[j] << 16);
            acc1.y += __uint_as_float(vb[j] & 0xFFFF0000u);
        }
        i0 += 8; i1 += 8;
    }
    for (; i0 + 8 <= dg0; i0 += 8) {
        unsigned va[8];
        #pragma unroll
        for (int j = 0; j < 8; ++j) va[j] = featb[((size_t)IDX0(i0 + j) << 6) + lane];
        #pragma unroll
        for (int j = 0; j < 8; ++j) {
            acc0.x += __uint_as_float(va[j] << 16);
            acc0.y += __uint_as_float(va[j] & 0xFFFF0000u);
        }
    }
    for (; i0 < dg0; ++i0) {
        unsigned v = featb[((size_t)IDX0(i0) << 6) + lane];
        acc0.x += __uint_as_float(v << 16);
        acc0.y += __uint_as_float(v & 0xFFFF0000u);
    }
    for (; i1 + 8 <= dg1; i1 += 8) {
        unsigned vb[8];
        #pragma unroll
        for (int j = 0; j < 8; ++j) vb[j] = featb[((size_t)IDX1(i1 + j) << 6) + lane];
        #pragma unroll
        for (int j = 0; j < 8; ++j) {
            acc1.x += __uint_as_float(vb[j] << 16);
            acc1.y += __uint_as_float(vb[j] & 0xFFFF0000u);
        }
    }
    for (; i1 < dg1; ++i1) {
        unsigned v = featb[((size_t)IDX1(i1) << 6) + lane];
        acc1.x += __uint_as_float(v << 16);
        acc1.y += __uint_as_float(v & 0xFFFF0000u);
    }
    #undef IDX0
    #undef IDX1

    {
        const float2 fd0 = reinterpret_cast<const float2*>(feat + (size_t)n0 * D)[lane];
        const float2 fd1 = reinterpret_cast<const float2*>(feat + (size_t)(n0 + 1) * D)[lane];
        const float inv0 = 1.0f / (float)max(dg0, 1);
        const float inv1 = 1.0f / (float)max(dg1, 1);
        xs[(wave * 2)     * XPITCH + lane * 2]     = acc0.x * fd0.x * inv0;
        xs[(wave * 2)     * XPITCH + lane * 2 + 1] = acc0.y * fd0.y * inv0;
        xs[(wave * 2 + 1) * XPITCH + lane * 2]     = acc1.x * fd1.x * inv1;
        xs[(wave * 2 + 1) * XPITCH + lane * 2 + 1] = acc1.y * fd1.y * inv1;
    }
    __syncthreads();

    // ---- MFMA GEMM: D[16 nodes][128 ch]; wave owns ntile = wave ----
    {
        const int arow = lane & 15;            // M index (node)
        const int aq   = lane >> 4;            // quad
        const int col  = lane & 15;            // N index within ntile

        short8 afrag[4];
        #pragma unroll
        for (int kt = 0; kt < 4; ++kt) {
            const float* xp = xs + arow * XPITCH + kt * 32 + aq * 8;
            union { short8 s; unsigned u[4]; } af;
            af.u[0] = pack2(xp[0], xp[1]);
            af.u[1] = pack2(xp[2], xp[3]);
            af.u[2] = pack2(xp[4], xp[5]);
            af.u[3] = pack2(xp[6], xp[7]);
            afrag[kt] = af.s;
        }

        float bo = bias[wave * 16 + col];
        float4v acc = (float4v){bo, bo, bo, bo};

        #pragma unroll
        for (int kt = 0; kt < 4; ++kt) {
            union { short8 s; uint4 u; } bf;
            bf.u = reinterpret_cast<const uint4*>(wfrag)[(wave * 4 + kt) * 64 + lane];
            acc = __builtin_amdgcn_mfma_f32_16x16x32_bf16(afrag[kt], bf.s, acc, 0, 0, 0);
        }

        // C/D layout: col = lane&15, row = (lane>>4)*4 + reg
        const int rbase = (lane >> 4) * 4;
        const int c = wave * 16 + col;
        #pragma unroll
        for (int r = 0; r < 4; ++r)
            out[(size_t)(node0 + rbase + r) * D + c] = acc[r];
    }
}

extern "C" void kernel_launch(void* const* d_in, const int* in_sizes, int n_in,
                              void* d_out, int out_size, void* d_ws, size_t ws_size,
                              hipStream_t stream)
{
    const float* feat = (const float*)d_in[0];
    const int*   src  = (const int*)  d_in[1];
    const int*   dst  = (const int*)  d_in[2];
    const float* W    = (const float*)d_in[3];
    const float* bias = (const float*)d_in[4];
    float* out = (float*)d_out;

    // Workspace (~15.6 MB), 16B-aligned segments. bucket directly before deg
    // so ONE memset zeroes both (bucket words must start 0 for atomicOr).
    unsigned* featb  = (unsigned*)d_ws;                        // [N*D/2]
    unsigned* wfrag  = featb + (size_t)N_NODES * D / 2;        // [8192]
    unsigned* bucket = wfrag + 8192;                           // [N*CAP/2] u32
    int*      deg    = (int*)(bucket + (size_t)N_NODES * (CAP / 2)); // [N]

    hipMemsetAsync(bucket, 0,
                   ((size_t)N_NODES * (CAP / 2) + N_NODES) * sizeof(int), stream);
    prep_kernel<<<PREP_GRID, 256, 0, stream>>>(feat, src, dst, W, featb, wfrag, deg, bucket);
    agg_gemm<<<N_NODES / 16, 512, 0, stream>>>(feat, featb, wfrag, deg, bucket, bias, out);
}

// Round 14
// 140.144 us; speedup vs baseline: 1.1526x; 1.1526x over previous
//
#include <hip/hip_runtime.h>

#define N_NODES 40000
#define N_EDGES 640000
#define D 128
#define CAP 64            // bucket slots/node (u16); in-deg ~ Poisson(16), P(>64) ~ 1e-13
#define PREP_GRID 1280    // 2 independent edge chains per thread
#define XPITCH 136        // xs row pitch (floats); 544 B rows, 32B-aligned

typedef __attribute__((ext_vector_type(8))) short short8;
typedef __attribute__((ext_vector_type(4))) float float4v;

// round-to-nearest-even fp32 -> bf16 bits
static __device__ __forceinline__ unsigned bf16_rne(float f) {
    unsigned u = __float_as_uint(f);
    return (u + 0x7FFFu + ((u >> 16) & 1u)) >> 16;
}
static __device__ __forceinline__ unsigned pack2(float a, float b) {
    return bf16_rne(a) | (bf16_rne(b) << 16);
}

// ---------------------------------------------------------------------------
// K1 (= R11 proven): (a) edge hist + u16 bucket scatter (rank = hist atomic
//     return; u16 = the one verified scatter win, R7->R8). Two independent
//     chains per thread. (b) fp32->bf16 feature pack; (c) W -> bf16
//     B-fragment order for the MFMA GEMM.
// ---------------------------------------------------------------------------
__global__ __launch_bounds__(256) void prep_kernel(
    const float* __restrict__ feat,
    const int*   __restrict__ src,
    const int*   __restrict__ dst,
    const float* __restrict__ W,
    unsigned*       __restrict__ featb,   // [N*D/2] packed 2xbf16
    unsigned*       __restrict__ wfrag,   // [8192] packed 2xbf16, frag order
    int*            __restrict__ deg,     // [N] zeroed by memset
    unsigned short* __restrict__ bucket)  // [N*CAP] u16 src indices
{
    const int g  = blockIdx.x * 256 + threadIdx.x;
    const int GT = PREP_GRID * 256;       // 327680

    // ---- edge phase: two independent chains per thread ----
    {
        const int e0 = g;                 // < 327680 < N_EDGES always
        const int e1 = g + GT;
        const bool h1 = e1 < N_EDGES;
        int d0 = dst[e0];
        int s0 = src[e0];
        int d1 = h1 ? dst[e1] : 0;
        int s1 = h1 ? src[e1] : 0;
        int r0 = atomicAdd(&deg[d0], 1);              // both atomics in flight
        int r1 = h1 ? atomicAdd(&deg[d1], 1) : CAP;   // before either store
        if (r0 < CAP) bucket[(size_t)d0 * CAP + r0] = (unsigned short)s0;
        if (r1 < CAP) bucket[(size_t)d1 * CAP + r1] = (unsigned short)s1;
    }

    // ---- bf16 feature pack (streams under other waves' atomic stalls) ----
    for (int i = g; i < N_NODES * D / 4; i += GT) {
        float4 f = reinterpret_cast<const float4*>(feat)[i];
        uint2 p;
        p.x = pack2(f.x, f.y);
        p.y = pack2(f.z, f.w);
        reinterpret_cast<uint2*>(featb)[i] = p;
    }

    // ---- W -> B-fragment order (8 ntiles x 4 ktiles x 64 lanes) ----
    if (g < 32 * 64) {
        const int tile = g >> 6, lane = g & 63;
        const int nt = tile >> 2, kt = tile & 3;
        const int n = nt * 16 + (lane & 15);
        const int k = kt * 32 + (lane >> 4) * 8;
        const float* wp = W + (size_t)n * D + k;
        uint4 p;
        p.x = pack2(wp[0], wp[1]);
        p.y = pack2(wp[2], wp[3]);
        p.z = pack2(wp[4], wp[5]);
        p.w = pack2(wp[6], wp[7]);
        reinterpret_cast<uint4*>(wfrag)[g] = p;
    }
}

// ---------------------------------------------------------------------------
// K2 (= R11 + occupancy hint): fused aggregate + MFMA linear. Block = 512
//     thr = 8 waves = 16 nodes. __launch_bounds__(512, 4) asks for 4 waves/EU
//     = 2 blocks/CU co-resident (R7 measured 42% occupancy on the
//     latency-bound gather; more resident waves = more gathers in flight).
//     Wave owns nodes {2w, 2w+1}; bucket rows preloaded (one coalesced read
//     each), indices via __shfl; the two nodes' gather loops INTERLEAVED
//     (16 gathers in flight). sum featb[src] * feat[n]/deg (factorized
//     u_mul_v) -> LDS xs. GEMM: wave w -> ntile w, 4x mfma_f32_16x16x32_bf16.
// ---------------------------------------------------------------------------
__global__ __launch_bounds__(512, 4) void agg_gemm(
    const float*          __restrict__ feat,
    const unsigned*       __restrict__ featb,
    const unsigned*       __restrict__ wfrag,
    const int*            __restrict__ deg,
    const unsigned short* __restrict__ bucket,
    const float*          __restrict__ bias,
    float*                __restrict__ out)
{
    __shared__ float xs[16 * XPITCH];   // 8704 B
    const int t     = threadIdx.x;
    const int wave  = t >> 6;           // 0..7
    const int lane  = t & 63;
    const int node0 = blockIdx.x * 16;

    const int n0  = node0 + wave * 2;
    const int dg0 = min(deg[n0],     CAP);
    const int dg1 = min(deg[n0 + 1], CAP);
    const unsigned iw0 = reinterpret_cast<const unsigned*>(bucket + (size_t)n0 * CAP)[lane & 31];
    const unsigned iw1 = reinterpret_cast<const unsigned*>(bucket + (size_t)(n0 + 1) * CAP)[lane & 31];

    float2 acc0 = make_float2(0.f, 0.f);
    float2 acc1 = make_float2(0.f, 0.f);

    #define IDX0(i) ({ int w_ = __shfl((int)iw0, (i) >> 1, 64); ((i) & 1) ? ((w_ >> 16) & 0xFFFF) : (w_ & 0xFFFF); })
    #define IDX1(i) ({ int w_ = __shfl((int)iw1, (i) >> 1, 64); ((i) & 1) ? ((w_ >> 16) & 0xFFFF) : (w_ & 0xFFFF); })

    int i0 = 0, i1 = 0;
    while (i0 + 8 <= dg0 && i1 + 8 <= dg1) {   // 16 gathers in flight
        unsigned va[8], vb[8];
        #pragma unroll
        for (int j = 0; j < 8; ++j) va[j] = featb[((size_t)IDX0(i0 + j) << 6) + lane];
        #pragma unroll
        for (int j = 0; j < 8; ++j) vb[j] = featb[((size_t)IDX1(i1 + j) << 6) + lane];
        #pragma unroll
        for (int j = 0; j < 8; ++j) {
            acc0.x += __uint_as_float(va[j] << 16);
            acc0.y += __uint_as_float(va[j] & 0xFFFF0000u);
            acc1.x += __uint_as_float(vb[j] << 16);
            acc1.y += __uint_as_float(vb[j] & 0xFFFF0000u);
        }
        i0 += 8; i1 += 8;
    }
    for (; i0 + 8 <= dg0; i0 += 8) {
        unsigned va[8];
        #pragma unroll
        for (int j = 0; j < 8; ++j) va[j] = featb[((size_t)IDX0(i0 + j) << 6) + lane];
        #pragma unroll
        for (int j = 0; j < 8; ++j) {
            acc0.x += __uint_as_float(va[j] << 16);
            acc0.y += __uint_as_float(va[j] & 0xFFFF0000u);
        }
    }
    for (; i0 < dg0; ++i0) {
        unsigned v = featb[((size_t)IDX0(i0) << 6) + lane];
        acc0.x += __uint_as_float(v << 16);
        acc0.y += __uint_as_float(v & 0xFFFF0000u);
    }
    for (; i1 + 8 <= dg1; i1 += 8) {
        unsigned vb[8];
        #pragma unroll
        for (int j = 0; j < 8; ++j) vb[j] = featb[((size_t)IDX1(i1 + j) << 6) + lane];
        #pragma unroll
        for (int j = 0; j < 8; ++j) {
            acc1.x += __uint_as_float(vb[j] << 16);
            acc1.y += __uint_as_float(vb[j] & 0xFFFF0000u);
        }
    }
    for (; i1 < dg1; ++i1) {
        unsigned v = featb[((size_t)IDX1(i1) << 6) + lane];
        acc1.x += __uint_as_float(v << 16);
        acc1.y += __uint_as_float(v & 0xFFFF0000u);
    }
    #undef IDX0
    #undef IDX1

    {
        const float2 fd0 = reinterpret_cast<const float2*>(feat + (size_t)n0 * D)[lane];
        const float2 fd1 = reinterpret_cast<const float2*>(feat + (size_t)(n0 + 1) * D)[lane];
        const float inv0 = 1.0f / (float)max(dg0, 1);
        const float inv1 = 1.0f / (float)max(dg1, 1);
        xs[(wave * 2)     * XPITCH + lane * 2]     = acc0.x * fd0.x * inv0;
        xs[(wave * 2)     * XPITCH + lane * 2 + 1] = acc0.y * fd0.y * inv0;
        xs[(wave * 2 + 1) * XPITCH + lane * 2]     = acc1.x * fd1.x * inv1;
        xs[(wave * 2 + 1) * XPITCH + lane * 2 + 1] = acc1.y * fd1.y * inv1;
    }
    __syncthreads();

    // ---- MFMA GEMM: D[16 nodes][128 ch]; wave owns ntile = wave ----
    {
        const int arow = lane & 15;            // M index (node)
        const int aq   = lane >> 4;            // quad
        const int col  = lane & 15;            // N index within ntile

        short8 afrag[4];
        #pragma unroll
        for (int kt = 0; kt < 4; ++kt) {
            const float* xp = xs + arow * XPITCH + kt * 32 + aq * 8;
            union { short8 s; unsigned u[4]; } af;
            af.u[0] = pack2(xp[0], xp[1]);
            af.u[1] = pack2(xp[2], xp[3]);
            af.u[2] = pack2(xp[4], xp[5]);
            af.u[3] = pack2(xp[6], xp[7]);
            afrag[kt] = af.s;
        }

        float bo = bias[wave * 16 + col];
        float4v acc = (float4v){bo, bo, bo, bo};

        #pragma unroll
        for (int kt = 0; kt < 4; ++kt) {
            union { short8 s; uint4 u; } bf;
            bf.u = reinterpret_cast<const uint4*>(wfrag)[(wave * 4 + kt) * 64 + lane];
            acc = __builtin_amdgcn_mfma_f32_16x16x32_bf16(afrag[kt], bf.s, acc, 0, 0, 0);
        }

        // C/D layout: col = lane&15, row = (lane>>4)*4 + reg
        const int rbase = (lane >> 4) * 4;
        const int c = wave * 16 + col;
        #pragma unroll
        for (int r = 0; r < 4; ++r)
            out[(size_t)(node0 + rbase + r) * D + c] = acc[r];
    }
}

extern "C" void kernel_launch(void* const* d_in, const int* in_sizes, int n_in,
                              void* d_out, int out_size, void* d_ws, size_t ws_size,
                              hipStream_t stream)
{
    const float* feat = (const float*)d_in[0];
    const int*   src  = (const int*)  d_in[1];
    const int*   dst  = (const int*)  d_in[2];
    const float* W    = (const float*)d_in[3];
    const float* bias = (const float*)d_in[4];
    float* out = (float*)d_out;

    // Workspace (~15.6 MB), 16B-aligned segments:
    unsigned*       featb  = (unsigned*)d_ws;                        // [N*D/2]
    unsigned*       wfrag  = featb + (size_t)N_NODES * D / 2;        // [8192]
    unsigned short* bucket = (unsigned short*)(wfrag + 8192);        // [N*CAP] u16
    int*            deg    = (int*)(bucket + (size_t)N_NODES * CAP); // [N]

    hipMemsetAsync(deg, 0, N_NODES * sizeof(int), stream);
    prep_kernel<<<PREP_GRID, 256, 0, stream>>>(feat, src, dst, W, featb, wfrag, deg, bucket);
    agg_gemm<<<N_NODES / 16, 512, 0, stream>>>(feat, featb, wfrag, deg, bucket, bias, out);
}